// Round 9
// baseline (1916.659 us; speedup 1.0000x reference)
//
#include <hip/hip_runtime.h>
#include <hip/hip_bf16.h>

typedef unsigned int uint;
typedef unsigned short u16;

#define D_ 4096
#define H_ 32
#define DH 128
#define F_ 8192
#define V_ 8192
#define S_ 1024
#define M_ 512
#define L_ 2
#define KV_ (M_ + S_)

typedef __attribute__((ext_vector_type(8))) short s16x8;
typedef __attribute__((ext_vector_type(4))) float f32x4;
typedef __attribute__((ext_vector_type(4))) u16 u16x4;

__device__ __forceinline__ u16 f2bf(float f) {
    uint u = __float_as_uint(f);
    u += 0x7FFFu + ((u >> 16) & 1u);
    return (u16)(u >> 16);
}
__device__ __forceinline__ float bf2f(u16 h) {
    return __uint_as_float(((uint)h) << 16);
}
__device__ __forceinline__ void gload_lds16(const void* g, void* l) {
    __builtin_amdgcn_global_load_lds(
        (const __attribute__((address_space(1))) unsigned int*)g,
        (__attribute__((address_space(3))) unsigned int*)l, 16, 0, 0);
}

// ---------------- zero fill (f32) -------------------------------------------
__global__ void k_zero(float* __restrict__ dst, int n4) {
    int i = blockIdx.x * 256 + threadIdx.x;
    if (i < n4) ((float4*)dst)[i] = make_float4(0.f, 0.f, 0.f, 0.f);
}

// ---------------- embedding gather ------------------------------------------
__global__ void k_embed(const int* __restrict__ ids, const float* __restrict__ embed,
                        float* __restrict__ h) {
    int row = blockIdx.x;
    const float4* src = (const float4*)(embed + (size_t)ids[row] * D_);
    float4* dst = (float4*)(h + (size_t)row * D_);
    for (int i = threadIdx.x; i < D_ / 4; i += 256) dst[i] = src[i];
}

// ---------------- RMSNorm ---------------------------------------------------
__global__ __launch_bounds__(256) void k_rms(const float* __restrict__ hin,
                                             const float* __restrict__ w,
                                             u16* __restrict__ out) {
    int row = blockIdx.x, t = threadIdx.x;
    const float4* src = (const float4*)(hin + (size_t)row * D_);
    float4 v[4];
    float ss = 0.f;
#pragma unroll
    for (int i = 0; i < 4; ++i) {
        v[i] = src[t + 256 * i];
        ss += v[i].x * v[i].x + v[i].y * v[i].y + v[i].z * v[i].z + v[i].w * v[i].w;
    }
#pragma unroll
    for (int off = 32; off; off >>= 1) ss += __shfl_xor(ss, off);
    __shared__ float red[4];
    if ((t & 63) == 0) red[t >> 6] = ss;
    __syncthreads();
    float tot = red[0] + red[1] + red[2] + red[3];
    float sc = rsqrtf(tot * (1.0f / D_) + 1e-5f);
    const float4* wp = (const float4*)w;
    u16x4* op = (u16x4*)(out + (size_t)row * D_);
#pragma unroll
    for (int i = 0; i < 4; ++i) {
        float4 wv = wp[t + 256 * i];
        u16x4 o;
        o[0] = f2bf(v[i].x * sc * wv.x);
        o[1] = f2bf(v[i].y * sc * wv.y);
        o[2] = f2bf(v[i].z * sc * wv.z);
        o[3] = f2bf(v[i].w * sc * wv.w);
        op[t + 256 * i] = o;
    }
}

// ---------------- f32 -> bf16 convert ---------------------------------------
__global__ void k_cvt(const float* __restrict__ src, u16* __restrict__ dst, int n4) {
    int i = blockIdx.x * 256 + threadIdx.x;
    if (i < n4) {
        float4 v = ((const float4*)src)[i];
        u16x4 o;
        o[0] = f2bf(v.x); o[1] = f2bf(v.y); o[2] = f2bf(v.z); o[3] = f2bf(v.w);
        ((u16x4*)dst)[i] = o;
    }
}

// ---------------- silu(g)*u (bf16 in/out) -----------------------------------
__global__ void k_silu(const u16* __restrict__ G, const u16* __restrict__ U,
                       u16* __restrict__ out, int n8) {
    int i = blockIdx.x * 256 + threadIdx.x;
    if (i < n8) {
        s16x8 g = ((const s16x8*)G)[i];
        s16x8 u = ((const s16x8*)U)[i];
        s16x8 o;
#pragma unroll
        for (int j = 0; j < 8; ++j) {
            float gv = bf2f((u16)g[j]), uv = bf2f((u16)u[j]);
            o[j] = (short)f2bf(gv / (1.0f + __expf(-gv)) * uv);
        }
        ((s16x8*)out)[i] = o;
    }
}

// ---------------- RoPE cos/sin table ----------------------------------------
__global__ void k_ropetab(float* __restrict__ tab) {
    int pos = blockIdx.x, i = threadIdx.x;  // 64 threads
    float invf = powf(10000.0f, -(float)i * (1.0f / 64.0f));
    float ang = (float)pos * invf;
    tab[(size_t)pos * 128 + i * 2] = cosf(ang);
    tab[(size_t)pos * 128 + i * 2 + 1] = sinf(ang);
}

// ---------------- RoPE in-place (table-driven) ------------------------------
__global__ __launch_bounds__(256) void k_rope(u16* __restrict__ buf,
                                              const float* __restrict__ tab, int pos0) {
    int row = blockIdx.x, t = threadIdx.x;
    const float2* tp = (const float2*)(tab + (size_t)(pos0 + row) * 128);
    u16* p = buf + (size_t)row * D_;
#pragma unroll
    for (int j = 0; j < 8; ++j) {
        int pid = t + 256 * j;
        int hd = pid >> 6, i = pid & 63;
        float2 cs = tp[i];
        int base = hd * 128 + i;
        float v0 = bf2f(p[base]), v1 = bf2f(p[base + 64]);
        p[base] = f2bf(v0 * cs.x - v1 * cs.y);
        p[base + 64] = f2bf(v1 * cs.x + v0 * cs.y);
    }
}

// ---------------- transpose Vb [KV][D] -> VT [D][KV] ------------------------
__global__ __launch_bounds__(256) void k_transpose(const u16* __restrict__ src,
                                                   u16* __restrict__ dst) {
    __shared__ u16 tile[64][66];
    int tc = blockIdx.x * 64;
    int tr = blockIdx.y * 64;
    int t = threadIdx.x;
    int c = t & 63, r0 = t >> 6;
#pragma unroll
    for (int i = 0; i < 16; ++i) {
        int r = r0 + i * 4;
        tile[r][c] = src[(size_t)(tr + r) * D_ + tc + c];
    }
    __syncthreads();
#pragma unroll
    for (int i = 0; i < 16; ++i) {
        int r = r0 + i * 4;
        dst[(size_t)(tc + r) * KV_ + tr + c] = tile[c][r];
    }
}

// ======================= 8-phase 256x256 GEMM (bf16 both sides) ==============
// C[mrows x Nn] = A(bf16 [M][Kfull]) @ B(bf16 [N][Kfull])^T over K-range
// [koff, koff+Kstep) per z-slice (split-K via koff).
// T2 swizzle + af-hold (32 ds_read_b128/tile) + counted vmcnt(4) + setprio.
// EPI 0: bf16 store  1: f32 store  2: f32 atomicAdd (split-K accumulate)
struct GemmB8 {
    const u16* A[5];
    const u16* B[5];
    void* O[5];
    int mrows[5];
    int koff[5];
};

template <int EPI>
__global__ __launch_bounds__(512, 2) void k_gemm8(GemmB8 P, int Nn, int Kstep, int Kfull) {
    int z = blockIdx.z;
    size_t bm = blockIdx.y, bn = blockIdx.x;
    if ((int)(bm * 256) >= P.mrows[z]) return;
    const u16* A = P.A[z];
    const u16* Bw = P.B[z];
    const int koff = P.koff[z];
    __shared__ __align__(16) u16 AB[2][2][2][128][64];  // [buf][A/B][half][row][k]

    const int tid = threadIdx.x;
    const int lane = tid & 63, wid = tid >> 6;
    const int l16 = lane & 15, lh = lane >> 4;
    const int wrow = (wid >> 2) * 64;
    const int wcol = (wid & 3) * 32;
    const int nt = Kstep >> 6;

    const int grow0 = tid >> 3;
    const int gsw = ((tid & 7) ^ (grow0 & 7)) * 8;  // inverse-swizzled src group
    const u16* pA = A + (size_t)(bm * 256 + grow0) * Kfull + koff + gsw;
    const u16* pB = Bw + (size_t)(bn * 256 + grow0) * Kfull + koff + gsw;

    auto stage = [&](const u16* base, int mat, int h, int t) {
        if (t >= nt) return;
        const u16* g = base + (size_t)(h * 128) * Kfull + t * 64;
        u16* l = &AB[t & 1][mat][h][0][0] + tid * 8;  // linear dest
        gload_lds16(g, l);
        gload_lds16(g + (size_t)64 * Kfull, l + 4096);
    };

    f32x4 acc[4][4][2];
#pragma unroll
    for (int q = 0; q < 4; ++q)
#pragma unroll
        for (int mf = 0; mf < 4; ++mf)
#pragma unroll
            for (int nf = 0; nf < 2; ++nf)
#pragma unroll
                for (int e = 0; e < 4; ++e) acc[q][mf][nf][e] = 0.f;

    // prologue: T0.{A0,B0,A1,B1}, T1.{A0,B0}
    stage(pA, 0, 0, 0); stage(pB, 1, 0, 0);
    stage(pA, 0, 1, 0); stage(pB, 1, 1, 0);
    stage(pA, 0, 0, 1); stage(pB, 1, 0, 1);
    asm volatile("s_waitcnt vmcnt(4)" ::: "memory");  // T0 fully landed
    __builtin_amdgcn_s_barrier();
    asm volatile("" ::: "memory");

    for (int T = 0; T < nt; ++T) {
        const int cb = T & 1;
        s16x8 af[4][2], bb[2][2];

        // -------- q0: read af(qm=0)+bb(qn=0); stage (T+1).A1 --------
#pragma unroll
        for (int kk = 0; kk < 2; ++kk) {
            const int sw = ((kk * 4 + lh) ^ (l16 & 7)) * 8;
#pragma unroll
            for (int mf = 0; mf < 4; ++mf)
                af[mf][kk] = *(const s16x8*)(&AB[cb][0][0][wrow + mf * 16 + l16][sw]);
#pragma unroll
            for (int nf = 0; nf < 2; ++nf)
                bb[nf][kk] = *(const s16x8*)(&AB[cb][1][0][wcol + nf * 16 + l16][sw]);
        }
        stage(pA, 0, 1, T + 1);
        asm volatile("" ::: "memory");
        __builtin_amdgcn_s_barrier();
        asm volatile("" ::: "memory");
        __builtin_amdgcn_s_setprio(1);
#pragma unroll
        for (int kk = 0; kk < 2; ++kk)
#pragma unroll
            for (int mf = 0; mf < 4; ++mf)
#pragma unroll
                for (int nf = 0; nf < 2; ++nf)
                    acc[0][mf][nf] = __builtin_amdgcn_mfma_f32_16x16x32_bf16(
                        af[mf][kk], bb[nf][kk], acc[0][mf][nf], 0, 0, 0);
        __builtin_amdgcn_s_setprio(0);
        asm volatile("" ::: "memory");
        __builtin_amdgcn_s_barrier();
        asm volatile("" ::: "memory");

        // -------- q1: read bb(qn=1) only (af held); stage (T+1).B1 --------
#pragma unroll
        for (int kk = 0; kk < 2; ++kk) {
            const int sw = ((kk * 4 + lh) ^ (l16 & 7)) * 8;
#pragma unroll
            for (int nf = 0; nf < 2; ++nf)
                bb[nf][kk] = *(const s16x8*)(&AB[cb][1][1][wcol + nf * 16 + l16][sw]);
        }
        stage(pB, 1, 1, T + 1);
        asm volatile("" ::: "memory");
        __builtin_amdgcn_s_barrier();
        asm volatile("" ::: "memory");
        __builtin_amdgcn_s_setprio(1);
#pragma unroll
        for (int kk = 0; kk < 2; ++kk)
#pragma unroll
            for (int mf = 0; mf < 4; ++mf)
#pragma unroll
                for (int nf = 0; nf < 2; ++nf)
                    acc[1][mf][nf] = __builtin_amdgcn_mfma_f32_16x16x32_bf16(
                        af[mf][kk], bb[nf][kk], acc[1][mf][nf], 0, 0, 0);
        __builtin_amdgcn_s_setprio(0);
        asm volatile("" ::: "memory");
        __builtin_amdgcn_s_barrier();
        asm volatile("" ::: "memory");

        // -------- q2: read af(qm=1)+bb(qn=0); stage (T+2).A0 --------
#pragma unroll
        for (int kk = 0; kk < 2; ++kk) {
            const int sw = ((kk * 4 + lh) ^ (l16 & 7)) * 8;
#pragma unroll
            for (int mf = 0; mf < 4; ++mf)
                af[mf][kk] = *(const s16x8*)(&AB[cb][0][1][wrow + mf * 16 + l16][sw]);
#pragma unroll
            for (int nf = 0; nf < 2; ++nf)
                bb[nf][kk] = *(const s16x8*)(&AB[cb][1][0][wcol + nf * 16 + l16][sw]);
        }
        stage(pA, 0, 0, T + 2);
        asm volatile("" ::: "memory");
        __builtin_amdgcn_s_barrier();
        asm volatile("" ::: "memory");
        __builtin_amdgcn_s_setprio(1);
#pragma unroll
        for (int kk = 0; kk < 2; ++kk)
#pragma unroll
            for (int mf = 0; mf < 4; ++mf)
#pragma unroll
                for (int nf = 0; nf < 2; ++nf)
                    acc[2][mf][nf] = __builtin_amdgcn_mfma_f32_16x16x32_bf16(
                        af[mf][kk], bb[nf][kk], acc[2][mf][nf], 0, 0, 0);
        __builtin_amdgcn_s_setprio(0);
        asm volatile("" ::: "memory");
        __builtin_amdgcn_s_barrier();
        asm volatile("" ::: "memory");

        // -------- q3: read bb(qn=1) only (af held); stage (T+2).B0; vmcnt ----
#pragma unroll
        for (int kk = 0; kk < 2; ++kk) {
            const int sw = ((kk * 4 + lh) ^ (l16 & 7)) * 8;
#pragma unroll
            for (int nf = 0; nf < 2; ++nf)
                bb[nf][kk] = *(const s16x8*)(&AB[cb][1][1][wcol + nf * 16 + l16][sw]);
        }
        stage(pB, 1, 0, T + 2);
        asm volatile("" ::: "memory");
        __builtin_amdgcn_s_barrier();
        asm volatile("" ::: "memory");
        __builtin_amdgcn_s_setprio(1);
#pragma unroll
        for (int kk = 0; kk < 2; ++kk)
#pragma unroll
            for (int mf = 0; mf < 4; ++mf)
#pragma unroll
                for (int nf = 0; nf < 2; ++nf)
                    acc[3][mf][nf] = __builtin_amdgcn_mfma_f32_16x16x32_bf16(
                        af[mf][kk], bb[nf][kk], acc[3][mf][nf], 0, 0, 0);
        __builtin_amdgcn_s_setprio(0);
        if (T < nt - 2) asm volatile("s_waitcnt vmcnt(4)" ::: "memory");
        else if (T == nt - 2) asm volatile("s_waitcnt vmcnt(0)" ::: "memory");
        asm volatile("" ::: "memory");
        __builtin_amdgcn_s_barrier();
        asm volatile("" ::: "memory");
    }

    void* Oo = P.O[z];
#pragma unroll
    for (int q = 0; q < 4; ++q) {
        const int qm = q >> 1, qn = q & 1;
#pragma unroll
        for (int mf = 0; mf < 4; ++mf) {
#pragma unroll
            for (int nf = 0; nf < 2; ++nf) {
#pragma unroll
                for (int rr = 0; rr < 4; ++rr) {
                    int grow = (int)bm * 256 + qm * 128 + wrow + mf * 16 + lh * 4 + rr;
                    int gcol = (int)bn * 256 + qn * 128 + wcol + nf * 16 + l16;
                    size_t idx = (size_t)grow * Nn + gcol;
                    float v = acc[q][mf][nf][rr];
                    if constexpr (EPI == 0) ((u16*)Oo)[idx] = f2bf(v);
                    else if constexpr (EPI == 1) ((float*)Oo)[idx] = v;
                    else atomicAdd((float*)Oo + idx, v);
                }
            }
        }
    }
}

// ---------------- flash attention: 1 wave per (16 q-rows, head) -------------
__global__ __launch_bounds__(64) void k_attn(const u16* __restrict__ Qb,
                                             const u16* __restrict__ Kb,
                                             const u16* __restrict__ VT,
                                             u16* __restrict__ Ob) {
    int qt = blockIdx.x, hd = blockIdx.y;
    int lane = threadIdx.x, l16 = lane & 15, lh = lane >> 4;
    __shared__ __align__(16) float Pl[16 * 36];

    s16x8 qf[4];
#pragma unroll
    for (int c = 0; c < 4; ++c)
        qf[c] = *(const s16x8*)(Qb + (size_t)(qt * 16 + l16) * D_ + hd * DH + c * 32 + lh * 8);

    f32x4 o[8];
#pragma unroll
    for (int dc = 0; dc < 8; ++dc)
#pragma unroll
        for (int e = 0; e < 4; ++e) o[dc][e] = 0.f;
    float m[4], lsum[4];
#pragma unroll
    for (int r = 0; r < 4; ++r) { m[r] = -1e30f; lsum[r] = 0.f; }

    const float scale = 0.08838834764831845f;
    int qbase = M_ + qt * 16;
    int nkb = (M_ + qt * 16 + 16 + 31) >> 5;

    for (int kb = 0; kb < nkb; ++kb) {
        f32x4 s0, s1;
#pragma unroll
        for (int e = 0; e < 4; ++e) { s0[e] = 0.f; s1[e] = 0.f; }
#pragma unroll
        for (int c = 0; c < 4; ++c) {
            s16x8 kf0 = *(const s16x8*)(Kb + (size_t)(kb * 32 + l16) * D_ + hd * DH + c * 32 + lh * 8);
            s16x8 kf1 = *(const s16x8*)(Kb + (size_t)(kb * 32 + 16 + l16) * D_ + hd * DH + c * 32 + lh * 8);
            s0 = __builtin_amdgcn_mfma_f32_16x16x32_bf16(qf[c], kf0, s0, 0, 0, 0);
            s1 = __builtin_amdgcn_mfma_f32_16x16x32_bf16(qf[c], kf1, s1, 0, 0, 0);
        }
        int kp0 = kb * 32 + l16, kp1 = kp0 + 16;
        float pm[4];
#pragma unroll
        for (int r = 0; r < 4; ++r) {
            int qp = qbase + lh * 4 + r;
            float v0 = s0[r] * scale; if (kp0 > qp) v0 = -1e30f;
            float v1 = s1[r] * scale; if (kp1 > qp) v1 = -1e30f;
            s0[r] = v0; s1[r] = v1;
            pm[r] = fmaxf(v0, v1);
        }
#pragma unroll
        for (int r = 0; r < 4; ++r) {
#pragma unroll
            for (int off = 8; off; off >>= 1) pm[r] = fmaxf(pm[r], __shfl_xor(pm[r], off));
        }
        float alpha[4];
#pragma unroll
        for (int r = 0; r < 4; ++r) {
            float mn = fmaxf(m[r], pm[r]);
            alpha[r] = __expf(m[r] - mn);
            m[r] = mn;
            float p0 = __expf(s0[r] - mn), p1 = __expf(s1[r] - mn);
            s0[r] = p0; s1[r] = p1;
            float t = p0 + p1;
#pragma unroll
            for (int off = 8; off; off >>= 1) t += __shfl_xor(t, off);
            lsum[r] = lsum[r] * alpha[r] + t;
        }
#pragma unroll
        for (int r = 0; r < 4; ++r) {
            Pl[(lh * 4 + r) * 36 + l16] = s0[r];
            Pl[(lh * 4 + r) * 36 + 16 + l16] = s1[r];
        }
        __syncthreads();
        s16x8 pf;
        {
            const f32x4* pp = (const f32x4*)(Pl + l16 * 36 + lh * 8);
            f32x4 a = pp[0], b = pp[1];
            pf[0] = (short)f2bf(a[0]); pf[1] = (short)f2bf(a[1]);
            pf[2] = (short)f2bf(a[2]); pf[3] = (short)f2bf(a[3]);
            pf[4] = (short)f2bf(b[0]); pf[5] = (short)f2bf(b[1]);
            pf[6] = (short)f2bf(b[2]); pf[7] = (short)f2bf(b[3]);
        }
        __syncthreads();
#pragma unroll
        for (int dc = 0; dc < 8; ++dc) {
#pragma unroll
            for (int r = 0; r < 4; ++r) o[dc][r] *= alpha[r];
        }
#pragma unroll
        for (int dc = 0; dc < 8; ++dc) {
            s16x8 vf = *(const s16x8*)(VT + (size_t)(hd * DH + dc * 16 + l16) * KV_ + kb * 32 + lh * 8);
            o[dc] = __builtin_amdgcn_mfma_f32_16x16x32_bf16(pf, vf, o[dc], 0, 0, 0);
        }
    }
#pragma unroll
    for (int dc = 0; dc < 8; ++dc) {
#pragma unroll
        for (int r = 0; r < 4; ++r) {
            float val = o[dc][r] / lsum[r];
            Ob[(size_t)(qt * 16 + lh * 4 + r) * D_ + hd * DH + dc * 16 + l16] = f2bf(val);
        }
    }
}

// ---------------- launch ----------------------------------------------------
extern "C" void kernel_launch(void* const* d_in, const int* in_sizes, int n_in,
                              void* d_out, int out_size, void* d_ws, size_t ws_size,
                              hipStream_t stream) {
    const int* ids = (const int*)d_in[0];
    const float* memory = (const float*)d_in[1];
    const float* embed = (const float*)d_in[2];
    const float* Wq = (const float*)d_in[3];
    const float* Wk = (const float*)d_in[4];
    const float* Wv = (const float*)d_in[5];
    const float* Wo = (const float*)d_in[6];
    const float* Wg = (const float*)d_in[7];
    const float* Wu = (const float*)d_in[8];
    const float* Wd = (const float*)d_in[9];
    const float* Wmk = (const float*)d_in[10];
    const float* Wmv = (const float*)d_in[11];
    const float* ln1 = (const float*)d_in[12];
    const float* ln2 = (const float*)d_in[13];
    const float* normw = (const float*)d_in[14];
    const float* lm = (const float*)d_in[15];

    char* ws = (char*)d_ws;
    float* h   = (float*)(ws + 0x0000000);   // 16.78 MB f32 [S][D]
    u16* xb    = (u16*)(ws + 0x1000000);     // 8.39 MB bf16 [S][D]
    float* tab = (float*)(ws + 0x1800000);   // 0.79 MB
    u16* memb  = (u16*)(ws + 0x1900000);     // 4.19 MB
    u16* Qb    = (u16*)(ws + 0x1E00000);     // 8.39 MB
    u16* Kb    = (u16*)(ws + 0x2600000);     // 12.58 MB [KV][D]
    u16* Vb    = (u16*)(ws + 0x3200000);     // 12.58 MB
    u16* VT    = (u16*)(ws + 0x3E00000);     // 12.58 MB [D][KV]
    u16* Ob    = (u16*)(ws + 0x4A00000);     // 8.39 MB
    // FFN overlays (Qb..Ob dead then):
    u16* Gb16  = (u16*)(ws + 0x1E00000);     // 16.78 MB bf16 [S][F]
    u16* Ub16  = (u16*)(ws + 0x2E00000);     // 16.78 MB bf16 [S][F]
    u16* tb    = (u16*)(ws + 0x3E00000);     // 16.78 MB bf16 [S][F]
    // bf16 weights (converted once per call):
    u16* Wqb  = (u16*)(ws + 0x07000000);
    u16* Wkb  = (u16*)(ws + 0x0B000000);
    u16* Wvb  = (u16*)(ws + 0x0F000000);
    u16* Wob  = (u16*)(ws + 0x13000000);
    u16* Wmkb = (u16*)(ws + 0x17000000);
    u16* Wmvb = (u16*)(ws + 0x1B000000);
    u16* Wgb  = (u16*)(ws + 0x1F000000);
    u16* Wub  = (u16*)(ws + 0x27000000);
    u16* Wdb  = (u16*)(ws + 0x2F000000);
    u16* lmb  = (u16*)(ws + 0x37000000);     // end 0x3B000000

    // ---- weight conversion (f32 -> bf16, RNE) ----
    const int nDD = L_ * D_ * D_ / 4, nFD = L_ * F_ * D_ / 4, nVD = V_ * D_ / 4;
    k_cvt<<<(nDD + 255) / 256, 256, 0, stream>>>(Wq, Wqb, nDD);
    k_cvt<<<(nDD + 255) / 256, 256, 0, stream>>>(Wk, Wkb, nDD);
    k_cvt<<<(nDD + 255) / 256, 256, 0, stream>>>(Wv, Wvb, nDD);
    k_cvt<<<(nDD + 255) / 256, 256, 0, stream>>>(Wo, Wob, nDD);
    k_cvt<<<(nDD + 255) / 256, 256, 0, stream>>>(Wmk, Wmkb, nDD);
    k_cvt<<<(nDD + 255) / 256, 256, 0, stream>>>(Wmv, Wmvb, nDD);
    k_cvt<<<(nFD + 255) / 256, 256, 0, stream>>>(Wg, Wgb, nFD);
    k_cvt<<<(nFD + 255) / 256, 256, 0, stream>>>(Wu, Wub, nFD);
    k_cvt<<<(nFD + 255) / 256, 256, 0, stream>>>(Wd, Wdb, nFD);
    k_cvt<<<(nVD + 255) / 256, 256, 0, stream>>>(lm, lmb, nVD);

    k_zero<<<(S_ * V_ / 4 + 255) / 256, 256, 0, stream>>>((float*)d_out, S_ * V_ / 4);
    k_embed<<<S_, 256, 0, stream>>>(ids, embed, h);
    k_ropetab<<<KV_, 64, 0, stream>>>(tab);

    for (int l = 0; l < L_; ++l) {
        const size_t oDD = (size_t)l * D_ * D_;
        const size_t oFD = (size_t)l * F_ * D_;

        k_rms<<<S_, 256, 0, stream>>>(h, ln1 + l * D_, xb);
        k_cvt<<<(M_ * D_ / 4 + 255) / 256, 256, 0, stream>>>(
            memory + (size_t)l * M_ * D_, memb, M_ * D_ / 4);

        // QKV + memory-KV: 8-phase 256^2, 5 z-slices (256 live blocks)
        GemmB8 g1{};
        g1.A[0] = xb;   g1.B[0] = Wqb + oDD;  g1.O[0] = Qb;                    g1.mrows[0] = S_;
        g1.A[1] = xb;   g1.B[1] = Wkb + oDD;  g1.O[1] = Kb + (size_t)M_ * D_;  g1.mrows[1] = S_;
        g1.A[2] = xb;   g1.B[2] = Wvb + oDD;  g1.O[2] = Vb + (size_t)M_ * D_;  g1.mrows[2] = S_;
        g1.A[3] = memb; g1.B[3] = Wmkb + oDD; g1.O[3] = Kb;                    g1.mrows[3] = M_;
        g1.A[4] = memb; g1.B[4] = Wmvb + oDD; g1.O[4] = Vb;                    g1.mrows[4] = M_;
        k_gemm8<0><<<dim3(D_ / 256, S_ / 256, 5), 512, 0, stream>>>(g1, D_, D_, D_);

        k_rope<<<S_, 256, 0, stream>>>(Qb, tab, M_);
        k_rope<<<KV_, 256, 0, stream>>>(Kb, tab, 0);
        k_transpose<<<dim3(D_ / 64, KV_ / 64), 256, 0, stream>>>(Vb, VT);
        k_attn<<<dim3(S_ / 16, H_), 64, 0, stream>>>(Qb, Kb, VT, Ob);

        // h += Ob @ Wo^T  (8-phase, split-K=4 -> 256 blocks, atomicAdd)
        GemmB8 g2{};
        for (int s = 0; s < 4; ++s) {
            g2.A[s] = Ob; g2.B[s] = Wob + oDD; g2.O[s] = h;
            g2.mrows[s] = S_; g2.koff[s] = s * 1024;
        }
        k_gemm8<2><<<dim3(D_ / 256, S_ / 256, 4), 512, 0, stream>>>(g2, D_, 1024, D_);

        // FFN
        k_rms<<<S_, 256, 0, stream>>>(h, ln2 + l * D_, xb);
        GemmB8 g3{};
        g3.A[0] = xb; g3.B[0] = Wgb + oFD; g3.O[0] = Gb16; g3.mrows[0] = S_;
        g3.A[1] = xb; g3.B[1] = Wub + oFD; g3.O[1] = Ub16; g3.mrows[1] = S_;
        k_gemm8<0><<<dim3(F_ / 256, S_ / 256, 2), 512, 0, stream>>>(g3, F_, D_, D_);
        k_silu<<<(S_ * F_ / 8 + 255) / 256, 256, 0, stream>>>(Gb16, Ub16, tb, S_ * F_ / 8);
        // h += t @ Wd^T  (8-phase, split-K=4 -> 256 blocks, atomicAdd)
        GemmB8 g5{};
        for (int s = 0; s < 4; ++s) {
            g5.A[s] = tb; g5.B[s] = Wdb + oFD; g5.O[s] = h;
            g5.mrows[s] = S_; g5.koff[s] = s * 2048;
        }
        k_gemm8<2><<<dim3(D_ / 256, S_ / 256, 4), 512, 0, stream>>>(g5, D_, 2048, F_);
    }

    k_rms<<<S_, 256, 0, stream>>>(h, normw, xb);
    // logits: 8-phase, split-K=2 -> 256 blocks, atomicAdd into zeroed d_out
    GemmB8 g6{};
    for (int s = 0; s < 2; ++s) {
        g6.A[s] = xb; g6.B[s] = lmb; g6.O[s] = (float*)d_out;
        g6.mrows[s] = S_; g6.koff[s] = s * 2048;
    }
    k_gemm8<2><<<dim3(V_ / 256, S_ / 256, 2), 512, 0, stream>>>(g6, V_, 2048, D_);
}

// Round 10
// 1888.835 us; speedup vs baseline: 1.0147x; 1.0147x over previous
//
#include <hip/hip_runtime.h>
#include <hip/hip_bf16.h>

typedef unsigned int uint;
typedef unsigned short u16;

#define D_ 4096
#define H_ 32
#define DH 128
#define F_ 8192
#define V_ 8192
#define S_ 1024
#define M_ 512
#define L_ 2
#define KV_ (M_ + S_)

typedef __attribute__((ext_vector_type(8))) short s16x8;
typedef __attribute__((ext_vector_type(4))) float f32x4;
typedef __attribute__((ext_vector_type(4))) u16 u16x4;

__device__ __forceinline__ u16 f2bf(float f) {
    uint u = __float_as_uint(f);
    u += 0x7FFFu + ((u >> 16) & 1u);
    return (u16)(u >> 16);
}
__device__ __forceinline__ float bf2f(u16 h) {
    return __uint_as_float(((uint)h) << 16);
}
__device__ __forceinline__ void gload_lds16(const void* g, void* l) {
    __builtin_amdgcn_global_load_lds(
        (const __attribute__((address_space(1))) unsigned int*)g,
        (__attribute__((address_space(3))) unsigned int*)l, 16, 0, 0);
}

// ---------------- embedding gather ------------------------------------------
__global__ void k_embed(const int* __restrict__ ids, const float* __restrict__ embed,
                        float* __restrict__ h) {
    int row = blockIdx.x;
    const float4* src = (const float4*)(embed + (size_t)ids[row] * D_);
    float4* dst = (float4*)(h + (size_t)row * D_);
    for (int i = threadIdx.x; i < D_ / 4; i += 256) dst[i] = src[i];
}

// ---------------- RMSNorm (plain) -------------------------------------------
__global__ __launch_bounds__(256) void k_rms(const float* __restrict__ hin,
                                             const float* __restrict__ w,
                                             u16* __restrict__ out) {
    int row = blockIdx.x, t = threadIdx.x;
    const float4* src = (const float4*)(hin + (size_t)row * D_);
    float4 v[4];
    float ss = 0.f;
#pragma unroll
    for (int i = 0; i < 4; ++i) {
        v[i] = src[t + 256 * i];
        ss += v[i].x * v[i].x + v[i].y * v[i].y + v[i].z * v[i].z + v[i].w * v[i].w;
    }
#pragma unroll
    for (int off = 32; off; off >>= 1) ss += __shfl_xor(ss, off);
    __shared__ float red[4];
    if ((t & 63) == 0) red[t >> 6] = ss;
    __syncthreads();
    float tot = red[0] + red[1] + red[2] + red[3];
    float sc = rsqrtf(tot * (1.0f / D_) + 1e-5f);
    const float4* wp = (const float4*)w;
    u16x4* op = (u16x4*)(out + (size_t)row * D_);
#pragma unroll
    for (int i = 0; i < 4; ++i) {
        float4 wv = wp[t + 256 * i];
        u16x4 o;
        o[0] = f2bf(v[i].x * sc * wv.x);
        o[1] = f2bf(v[i].y * sc * wv.y);
        o[2] = f2bf(v[i].z * sc * wv.z);
        o[3] = f2bf(v[i].w * sc * wv.w);
        op[t + 256 * i] = o;
    }
}

// ---------------- fused: h += P0 + P1, then rms(h)*w -> xb ------------------
__global__ __launch_bounds__(256) void k_addrms(float* __restrict__ hio,
                                                const float* __restrict__ p0,
                                                const float* __restrict__ p1,
                                                const float* __restrict__ w,
                                                u16* __restrict__ out) {
    int row = blockIdx.x, t = threadIdx.x;
    float4* hp = (float4*)(hio + (size_t)row * D_);
    const float4* q0 = (const float4*)(p0 + (size_t)row * D_);
    const float4* q1 = (const float4*)(p1 + (size_t)row * D_);
    float4 v[4];
    float ss = 0.f;
#pragma unroll
    for (int i = 0; i < 4; ++i) {
        float4 a = hp[t + 256 * i];
        float4 b = q0[t + 256 * i];
        float4 c = q1[t + 256 * i];
        v[i].x = a.x + b.x + c.x; v[i].y = a.y + b.y + c.y;
        v[i].z = a.z + b.z + c.z; v[i].w = a.w + b.w + c.w;
        hp[t + 256 * i] = v[i];
        ss += v[i].x * v[i].x + v[i].y * v[i].y + v[i].z * v[i].z + v[i].w * v[i].w;
    }
#pragma unroll
    for (int off = 32; off; off >>= 1) ss += __shfl_xor(ss, off);
    __shared__ float red[4];
    if ((t & 63) == 0) red[t >> 6] = ss;
    __syncthreads();
    float tot = red[0] + red[1] + red[2] + red[3];
    float sc = rsqrtf(tot * (1.0f / D_) + 1e-5f);
    const float4* wp = (const float4*)w;
    u16x4* op = (u16x4*)(out + (size_t)row * D_);
#pragma unroll
    for (int i = 0; i < 4; ++i) {
        float4 wv = wp[t + 256 * i];
        u16x4 o;
        o[0] = f2bf(v[i].x * sc * wv.x);
        o[1] = f2bf(v[i].y * sc * wv.y);
        o[2] = f2bf(v[i].z * sc * wv.z);
        o[3] = f2bf(v[i].w * sc * wv.w);
        op[t + 256 * i] = o;
    }
}

// ---------------- d_out = P0 + P1 (f32) -------------------------------------
__global__ void k_add2(const float* __restrict__ p0, const float* __restrict__ p1,
                       float* __restrict__ dst, int n4) {
    int i = blockIdx.x * 256 + threadIdx.x;
    if (i < n4) {
        float4 a = ((const float4*)p0)[i];
        float4 b = ((const float4*)p1)[i];
        ((float4*)dst)[i] = make_float4(a.x + b.x, a.y + b.y, a.z + b.z, a.w + b.w);
    }
}

// ---------------- merged f32 -> bf16 convert (all weights, 1 launch) --------
struct CvtBatch {
    const float* src[10];
    u16* dst[10];
    int off[11];  // float4-unit prefix offsets
};
__global__ void k_cvtall(CvtBatch C, int total4) {
    int i = blockIdx.x * 256 + threadIdx.x;
    if (i >= total4) return;
    int s = 0;
    while (i >= C.off[s + 1]) ++s;
    int j = i - C.off[s];
    float4 v = ((const float4*)C.src[s])[j];
    u16x4 o;
    o[0] = f2bf(v.x); o[1] = f2bf(v.y); o[2] = f2bf(v.z); o[3] = f2bf(v.w);
    ((u16x4*)C.dst[s])[j] = o;
}

// ---------------- f32 -> bf16 (memory slab) ---------------------------------
__global__ void k_cvt(const float* __restrict__ src, u16* __restrict__ dst, int n4) {
    int i = blockIdx.x * 256 + threadIdx.x;
    if (i < n4) {
        float4 v = ((const float4*)src)[i];
        u16x4 o;
        o[0] = f2bf(v.x); o[1] = f2bf(v.y); o[2] = f2bf(v.z); o[3] = f2bf(v.w);
        ((u16x4*)dst)[i] = o;
    }
}

// ---------------- silu(g)*u (bf16 in/out) -----------------------------------
__global__ void k_silu(const u16* __restrict__ G, const u16* __restrict__ U,
                       u16* __restrict__ out, int n8) {
    int i = blockIdx.x * 256 + threadIdx.x;
    if (i < n8) {
        s16x8 g = ((const s16x8*)G)[i];
        s16x8 u = ((const s16x8*)U)[i];
        s16x8 o;
#pragma unroll
        for (int j = 0; j < 8; ++j) {
            float gv = bf2f((u16)g[j]), uv = bf2f((u16)u[j]);
            o[j] = (short)f2bf(gv / (1.0f + __expf(-gv)) * uv);
        }
        ((s16x8*)out)[i] = o;
    }
}

// ---------------- RoPE cos/sin table ----------------------------------------
__global__ void k_ropetab(float* __restrict__ tab) {
    int pos = blockIdx.x, i = threadIdx.x;  // 64 threads
    float invf = powf(10000.0f, -(float)i * (1.0f / 64.0f));
    float ang = (float)pos * invf;
    tab[(size_t)pos * 128 + i * 2] = cosf(ang);
    tab[(size_t)pos * 128 + i * 2 + 1] = sinf(ang);
}

// ---------------- merged RoPE (Q rows then K rows, 1 launch) ----------------
__global__ __launch_bounds__(256) void k_rope2(u16* __restrict__ Qb, u16* __restrict__ Kb,
                                               const float* __restrict__ tab) {
    int b = blockIdx.x, t = threadIdx.x;
    u16* p;
    int pos;
    if (b < S_) { p = Qb + (size_t)b * D_; pos = M_ + b; }
    else        { p = Kb + (size_t)(b - S_) * D_; pos = b - S_; }
    const float2* tp = (const float2*)(tab + (size_t)pos * 128);
#pragma unroll
    for (int j = 0; j < 8; ++j) {
        int pid = t + 256 * j;
        int hd = pid >> 6, i = pid & 63;
        float2 cs = tp[i];
        int base = hd * 128 + i;
        float v0 = bf2f(p[base]), v1 = bf2f(p[base + 64]);
        p[base] = f2bf(v0 * cs.x - v1 * cs.y);
        p[base + 64] = f2bf(v1 * cs.x + v0 * cs.y);
    }
}

// ---------------- transpose Vb [KV][D] -> VT [D][KV] ------------------------
__global__ __launch_bounds__(256) void k_transpose(const u16* __restrict__ src,
                                                   u16* __restrict__ dst) {
    __shared__ u16 tile[64][66];
    int tc = blockIdx.x * 64;
    int tr = blockIdx.y * 64;
    int t = threadIdx.x;
    int c = t & 63, r0 = t >> 6;
#pragma unroll
    for (int i = 0; i < 16; ++i) {
        int r = r0 + i * 4;
        tile[r][c] = src[(size_t)(tr + r) * D_ + tc + c];
    }
    __syncthreads();
#pragma unroll
    for (int i = 0; i < 16; ++i) {
        int r = r0 + i * 4;
        dst[(size_t)(tc + r) * KV_ + tr + c] = tile[c][r];
    }
}

// ======================= 8-phase 256x256 GEMM (bf16 both sides) ==============
// T2 swizzle + af-hold (32 ds_read_b128/tile) + counted vmcnt(4) + setprio.
// EPI 0: bf16 store  1: f32 store
struct GemmB8 {
    const u16* A[5];
    const u16* B[5];
    void* O[5];
    int mrows[5];
};

template <int EPI>
__global__ __launch_bounds__(512, 2) void k_gemm8(GemmB8 P, int Nn, int Kfull) {
    int z = blockIdx.z;
    size_t bm = blockIdx.y, bn = blockIdx.x;
    if ((int)(bm * 256) >= P.mrows[z]) return;
    const u16* A = P.A[z];
    const u16* Bw = P.B[z];
    __shared__ __align__(16) u16 AB[2][2][2][128][64];  // [buf][A/B][half][row][k]

    const int tid = threadIdx.x;
    const int lane = tid & 63, wid = tid >> 6;
    const int l16 = lane & 15, lh = lane >> 4;
    const int wrow = (wid >> 2) * 64;
    const int wcol = (wid & 3) * 32;
    const int nt = Kfull >> 6;

    const int grow0 = tid >> 3;
    const int gsw = ((tid & 7) ^ (grow0 & 7)) * 8;  // inverse-swizzled src group
    const u16* pA = A + (size_t)(bm * 256 + grow0) * Kfull + gsw;
    const u16* pB = Bw + (size_t)(bn * 256 + grow0) * Kfull + gsw;

    auto stage = [&](const u16* base, int mat, int h, int t) {
        if (t >= nt) return;
        const u16* g = base + (size_t)(h * 128) * Kfull + t * 64;
        u16* l = &AB[t & 1][mat][h][0][0] + tid * 8;  // linear dest
        gload_lds16(g, l);
        gload_lds16(g + (size_t)64 * Kfull, l + 4096);
    };

    f32x4 acc[4][4][2];
#pragma unroll
    for (int q = 0; q < 4; ++q)
#pragma unroll
        for (int mf = 0; mf < 4; ++mf)
#pragma unroll
            for (int nf = 0; nf < 2; ++nf)
#pragma unroll
                for (int e = 0; e < 4; ++e) acc[q][mf][nf][e] = 0.f;

    // prologue: T0.{A0,B0,A1,B1}, T1.{A0,B0}
    stage(pA, 0, 0, 0); stage(pB, 1, 0, 0);
    stage(pA, 0, 1, 0); stage(pB, 1, 1, 0);
    stage(pA, 0, 0, 1); stage(pB, 1, 0, 1);
    asm volatile("s_waitcnt vmcnt(4)" ::: "memory");
    __builtin_amdgcn_s_barrier();
    asm volatile("" ::: "memory");

    for (int T = 0; T < nt; ++T) {
        const int cb = T & 1;
        s16x8 af[4][2], bb[2][2];

        // q0: read af(qm=0)+bb(qn=0); stage (T+1).A1
#pragma unroll
        for (int kk = 0; kk < 2; ++kk) {
            const int sw = ((kk * 4 + lh) ^ (l16 & 7)) * 8;
#pragma unroll
            for (int mf = 0; mf < 4; ++mf)
                af[mf][kk] = *(const s16x8*)(&AB[cb][0][0][wrow + mf * 16 + l16][sw]);
#pragma unroll
            for (int nf = 0; nf < 2; ++nf)
                bb[nf][kk] = *(const s16x8*)(&AB[cb][1][0][wcol + nf * 16 + l16][sw]);
        }
        stage(pA, 0, 1, T + 1);
        asm volatile("" ::: "memory");
        __builtin_amdgcn_s_barrier();
        asm volatile("" ::: "memory");
        __builtin_amdgcn_s_setprio(1);
#pragma unroll
        for (int kk = 0; kk < 2; ++kk)
#pragma unroll
            for (int mf = 0; mf < 4; ++mf)
#pragma unroll
                for (int nf = 0; nf < 2; ++nf)
                    acc[0][mf][nf] = __builtin_amdgcn_mfma_f32_16x16x32_bf16(
                        af[mf][kk], bb[nf][kk], acc[0][mf][nf], 0, 0, 0);
        __builtin_amdgcn_s_setprio(0);
        asm volatile("" ::: "memory");
        __builtin_amdgcn_s_barrier();
        asm volatile("" ::: "memory");

        // q1: read bb(qn=1) only (af held); stage (T+1).B1
#pragma unroll
        for (int kk = 0; kk < 2; ++kk) {
            const int sw = ((kk * 4 + lh) ^ (l16 & 7)) * 8;
#pragma unroll
            for (int nf = 0; nf < 2; ++nf)
                bb[nf][kk] = *(const s16x8*)(&AB[cb][1][1][wcol + nf * 16 + l16][sw]);
        }
        stage(pB, 1, 1, T + 1);
        asm volatile("" ::: "memory");
        __builtin_amdgcn_s_barrier();
        asm volatile("" ::: "memory");
        __builtin_amdgcn_s_setprio(1);
#pragma unroll
        for (int kk = 0; kk < 2; ++kk)
#pragma unroll
            for (int mf = 0; mf < 4; ++mf)
#pragma unroll
                for (int nf = 0; nf < 2; ++nf)
                    acc[1][mf][nf] = __builtin_amdgcn_mfma_f32_16x16x32_bf16(
                        af[mf][kk], bb[nf][kk], acc[1][mf][nf], 0, 0, 0);
        __builtin_amdgcn_s_setprio(0);
        asm volatile("" ::: "memory");
        __builtin_amdgcn_s_barrier();
        asm volatile("" ::: "memory");

        // q2: read af(qm=1)+bb(qn=0); stage (T+2).A0
#pragma unroll
        for (int kk = 0; kk < 2; ++kk) {
            const int sw = ((kk * 4 + lh) ^ (l16 & 7)) * 8;
#pragma unroll
            for (int mf = 0; mf < 4; ++mf)
                af[mf][kk] = *(const s16x8*)(&AB[cb][0][1][wrow + mf * 16 + l16][sw]);
#pragma unroll
            for (int nf = 0; nf < 2; ++nf)
                bb[nf][kk] = *(const s16x8*)(&AB[cb][1][0][wcol + nf * 16 + l16][sw]);
        }
        stage(pA, 0, 0, T + 2);
        asm volatile("" ::: "memory");
        __builtin_amdgcn_s_barrier();
        asm volatile("" ::: "memory");
        __builtin_amdgcn_s_setprio(1);
#pragma unroll
        for (int kk = 0; kk < 2; ++kk)
#pragma unroll
            for (int mf = 0; mf < 4; ++mf)
#pragma unroll
                for (int nf = 0; nf < 2; ++nf)
                    acc[2][mf][nf] = __builtin_amdgcn_mfma_f32_16x16x32_bf16(
                        af[mf][kk], bb[nf][kk], acc[2][mf][nf], 0, 0, 0);
        __builtin_amdgcn_s_setprio(0);
        asm volatile("" ::: "memory");
        __builtin_amdgcn_s_barrier();
        asm volatile("" ::: "memory");

        // q3: read bb(qn=1) only (af held); stage (T+2).B0; vmcnt
#pragma unroll
        for (int kk = 0; kk < 2; ++kk) {
            const int sw = ((kk * 4 + lh) ^ (l16 & 7)) * 8;
#pragma unroll
            for (int nf = 0; nf < 2; ++nf)
                bb[nf][kk] = *(const s16x8*)(&AB[cb][1][1][wcol + nf * 16 + l16][sw]);
        }
        stage(pB, 1, 0, T + 2);
        asm volatile("" ::: "memory");
        __builtin_amdgcn_s_barrier();
        asm volatile("" ::: "memory");
        __builtin_amdgcn_s_setprio(1);
#pragma unroll
        for (int kk = 0; kk < 2; ++kk)
#pragma unroll
            for (int mf = 0; mf < 4; ++mf)
#pragma unroll
                for (int nf = 0; nf < 2; ++nf)
                    acc[3][mf][nf] = __builtin_amdgcn_mfma_f32_16x16x32_bf16(
                        af[mf][kk], bb[nf][kk], acc[3][mf][nf], 0, 0, 0);
        __builtin_amdgcn_s_setprio(0);
        if (T < nt - 2) asm volatile("s_waitcnt vmcnt(4)" ::: "memory");
        else if (T == nt - 2) asm volatile("s_waitcnt vmcnt(0)" ::: "memory");
        asm volatile("" ::: "memory");
        __builtin_amdgcn_s_barrier();
        asm volatile("" ::: "memory");
    }

    void* Oo = P.O[z];
#pragma unroll
    for (int q = 0; q < 4; ++q) {
        const int qm = q >> 1, qn = q & 1;
#pragma unroll
        for (int mf = 0; mf < 4; ++mf) {
#pragma unroll
            for (int nf = 0; nf < 2; ++nf) {
#pragma unroll
                for (int rr = 0; rr < 4; ++rr) {
                    int grow = (int)bm * 256 + qm * 128 + wrow + mf * 16 + lh * 4 + rr;
                    int gcol = (int)bn * 256 + qn * 128 + wcol + nf * 16 + l16;
                    size_t idx = (size_t)grow * Nn + gcol;
                    float v = acc[q][mf][nf][rr];
                    if constexpr (EPI == 0) ((u16*)Oo)[idx] = f2bf(v);
                    else ((float*)Oo)[idx] = v;
                }
            }
        }
    }
}

// ======================= 2-phase 128x128 GEMM (bf16 both sides) ==============
// EPI 1: f32 store (split-K partials go to separate buffers — no atomics)
struct GemmB2 {
    const u16* A[5];
    const u16* B[5];
    void* O[5];
    int mrows[5];
    int koff[5];
};

template <int EPI>
__global__ __launch_bounds__(256) void k_gemm2(GemmB2 P, int Nn, int Kstep, int Kfull) {
    int z = blockIdx.z;
    size_t bm = blockIdx.y, bn = blockIdx.x;
    if ((int)(bm * 128) >= P.mrows[z]) return;
    const u16* A = P.A[z];
    const u16* Bw = P.B[z];
    int koff = P.koff[z];
    __shared__ __align__(16) u16 As[128 * 64];
    __shared__ __align__(16) u16 Bs[128 * 64];
    int tid = threadIdx.x;
    int lane = tid & 63, wid = tid >> 6;
    int l16 = lane & 15, lh = lane >> 4;
    int wm = (wid >> 1) * 64, wn = (wid & 1) * 64;

    const u16 *pA[4], *pB[4];
    int ldso[4];
#pragma unroll
    for (int i = 0; i < 4; ++i) {
        int c = tid + 256 * i;
        int r = c >> 3, s = c & 7;
        int ssw = (s ^ (r & 7)) * 8;
        pA[i] = A + (size_t)(bm * 128 + r) * Kfull + koff + ssw;
        pB[i] = Bw + (size_t)(bn * 128 + r) * Kfull + koff + ssw;
        ldso[i] = c * 8;
    }

    f32x4 acc[4][4];
#pragma unroll
    for (int i = 0; i < 4; ++i)
#pragma unroll
        for (int j = 0; j < 4; ++j)
#pragma unroll
            for (int e = 0; e < 4; ++e) acc[i][j][e] = 0.f;

    int nt = Kstep >> 6;
    for (int t = 0; t < nt; ++t) {
        int k0 = t << 6;
#pragma unroll
        for (int i = 0; i < 4; ++i) gload_lds16(pA[i] + k0, &As[ldso[i]]);
#pragma unroll
        for (int i = 0; i < 4; ++i) gload_lds16(pB[i] + k0, &Bs[ldso[i]]);
        __syncthreads();
#pragma unroll
        for (int kk = 0; kk < 2; ++kk) {
            int sidx = kk * 4 + lh;
            int sw = (sidx ^ (l16 & 7)) * 8;
            s16x8 af[4], bf4[4];
#pragma unroll
            for (int mi = 0; mi < 4; ++mi)
                af[mi] = *(const s16x8*)(&As[(wm + mi * 16 + l16) * 64 + sw]);
#pragma unroll
            for (int ni = 0; ni < 4; ++ni)
                bf4[ni] = *(const s16x8*)(&Bs[(wn + ni * 16 + l16) * 64 + sw]);
#pragma unroll
            for (int mi = 0; mi < 4; ++mi)
#pragma unroll
                for (int ni = 0; ni < 4; ++ni)
                    acc[mi][ni] = __builtin_amdgcn_mfma_f32_16x16x32_bf16(
                        af[mi], bf4[ni], acc[mi][ni], 0, 0, 0);
        }
        __syncthreads();
    }

    void* Oo = P.O[z];
#pragma unroll
    for (int mi = 0; mi < 4; ++mi) {
#pragma unroll
        for (int ni = 0; ni < 4; ++ni) {
#pragma unroll
            for (int r = 0; r < 4; ++r) {
                int grow = (int)bm * 128 + wm + mi * 16 + lh * 4 + r;
                int gcol = (int)bn * 128 + wn + ni * 16 + l16;
                size_t idx = (size_t)grow * Nn + gcol;
                ((float*)Oo)[idx] = acc[mi][ni][r];
            }
        }
    }
}

// ---------------- flash attention: 1 wave per (16 q-rows, head) -------------
__global__ __launch_bounds__(64) void k_attn(const u16* __restrict__ Qb,
                                             const u16* __restrict__ Kb,
                                             const u16* __restrict__ VT,
                                             u16* __restrict__ Ob) {
    int qt = blockIdx.x, hd = blockIdx.y;
    int lane = threadIdx.x, l16 = lane & 15, lh = lane >> 4;
    __shared__ __align__(16) float Pl[16 * 36];

    s16x8 qf[4];
#pragma unroll
    for (int c = 0; c < 4; ++c)
        qf[c] = *(const s16x8*)(Qb + (size_t)(qt * 16 + l16) * D_ + hd * DH + c * 32 + lh * 8);

    f32x4 o[8];
#pragma unroll
    for (int dc = 0; dc < 8; ++dc)
#pragma unroll
        for (int e = 0; e < 4; ++e) o[dc][e] = 0.f;
    float m[4], lsum[4];
#pragma unroll
    for (int r = 0; r < 4; ++r) { m[r] = -1e30f; lsum[r] = 0.f; }

    const float scale = 0.08838834764831845f;
    int qbase = M_ + qt * 16;
    int nkb = (M_ + qt * 16 + 16 + 31) >> 5;

    for (int kb = 0; kb < nkb; ++kb) {
        f32x4 s0, s1;
#pragma unroll
        for (int e = 0; e < 4; ++e) { s0[e] = 0.f; s1[e] = 0.f; }
#pragma unroll
        for (int c = 0; c < 4; ++c) {
            s16x8 kf0 = *(const s16x8*)(Kb + (size_t)(kb * 32 + l16) * D_ + hd * DH + c * 32 + lh * 8);
            s16x8 kf1 = *(const s16x8*)(Kb + (size_t)(kb * 32 + 16 + l16) * D_ + hd * DH + c * 32 + lh * 8);
            s0 = __builtin_amdgcn_mfma_f32_16x16x32_bf16(qf[c], kf0, s0, 0, 0, 0);
            s1 = __builtin_amdgcn_mfma_f32_16x16x32_bf16(qf[c], kf1, s1, 0, 0, 0);
        }
        int kp0 = kb * 32 + l16, kp1 = kp0 + 16;
        float pm[4];
#pragma unroll
        for (int r = 0; r < 4; ++r) {
            int qp = qbase + lh * 4 + r;
            float v0 = s0[r] * scale; if (kp0 > qp) v0 = -1e30f;
            float v1 = s1[r] * scale; if (kp1 > qp) v1 = -1e30f;
            s0[r] = v0; s1[r] = v1;
            pm[r] = fmaxf(v0, v1);
        }
#pragma unroll
        for (int r = 0; r < 4; ++r) {
#pragma unroll
            for (int off = 8; off; off >>= 1) pm[r] = fmaxf(pm[r], __shfl_xor(pm[r], off));
        }
        float alpha[4];
#pragma unroll
        for (int r = 0; r < 4; ++r) {
            float mn = fmaxf(m[r], pm[r]);
            alpha[r] = __expf(m[r] - mn);
            m[r] = mn;
            float p0 = __expf(s0[r] - mn), p1 = __expf(s1[r] - mn);
            s0[r] = p0; s1[r] = p1;
            float t = p0 + p1;
#pragma unroll
            for (int off = 8; off; off >>= 1) t += __shfl_xor(t, off);
            lsum[r] = lsum[r] * alpha[r] + t;
        }
#pragma unroll
        for (int r = 0; r < 4; ++r) {
            Pl[(lh * 4 + r) * 36 + l16] = s0[r];
            Pl[(lh * 4 + r) * 36 + 16 + l16] = s1[r];
        }
        __syncthreads();
        s16x8 pf;
        {
            const f32x4* pp = (const f32x4*)(Pl + l16 * 36 + lh * 8);
            f32x4 a = pp[0], b = pp[1];
            pf[0] = (short)f2bf(a[0]); pf[1] = (short)f2bf(a[1]);
            pf[2] = (short)f2bf(a[2]); pf[3] = (short)f2bf(a[3]);
            pf[4] = (short)f2bf(b[0]); pf[5] = (short)f2bf(b[1]);
            pf[6] = (short)f2bf(b[2]); pf[7] = (short)f2bf(b[3]);
        }
        __syncthreads();
#pragma unroll
        for (int dc = 0; dc < 8; ++dc) {
#pragma unroll
            for (int r = 0; r < 4; ++r) o[dc][r] *= alpha[r];
        }
#pragma unroll
        for (int dc = 0; dc < 8; ++dc) {
            s16x8 vf = *(const s16x8*)(VT + (size_t)(hd * DH + dc * 16 + l16) * KV_ + kb * 32 + lh * 8);
            o[dc] = __builtin_amdgcn_mfma_f32_16x16x32_bf16(pf, vf, o[dc], 0, 0, 0);
        }
    }
#pragma unroll
    for (int dc = 0; dc < 8; ++dc) {
#pragma unroll
        for (int r = 0; r < 4; ++r) {
            float val = o[dc][r] / lsum[r];
            Ob[(size_t)(qt * 16 + lh * 4 + r) * D_ + hd * DH + dc * 16 + l16] = f2bf(val);
        }
    }
}

// ---------------- launch ----------------------------------------------------
extern "C" void kernel_launch(void* const* d_in, const int* in_sizes, int n_in,
                              void* d_out, int out_size, void* d_ws, size_t ws_size,
                              hipStream_t stream) {
    const int* ids = (const int*)d_in[0];
    const float* memory = (const float*)d_in[1];
    const float* embed = (const float*)d_in[2];
    const float* Wq = (const float*)d_in[3];
    const float* Wk = (const float*)d_in[4];
    const float* Wv = (const float*)d_in[5];
    const float* Wo = (const float*)d_in[6];
    const float* Wg = (const float*)d_in[7];
    const float* Wu = (const float*)d_in[8];
    const float* Wd = (const float*)d_in[9];
    const float* Wmk = (const float*)d_in[10];
    const float* Wmv = (const float*)d_in[11];
    const float* ln1 = (const float*)d_in[12];
    const float* ln2 = (const float*)d_in[13];
    const float* normw = (const float*)d_in[14];
    const float* lm = (const float*)d_in[15];

    char* ws = (char*)d_ws;
    float* h   = (float*)(ws + 0x0000000);   // 16.78 MB f32 [S][D]
    u16* xb    = (u16*)(ws + 0x1000000);     // 8.39 MB bf16 [S][D]
    float* tab = (float*)(ws + 0x1800000);   // 0.79 MB
    u16* memb  = (u16*)(ws + 0x1900000);     // 4.19 MB
    u16* Qb    = (u16*)(ws + 0x1E00000);     // 8.39 MB
    u16* Kb    = (u16*)(ws + 0x2600000);     // 12.58 MB [KV][D]
    u16* Vb    = (u16*)(ws + 0x3200000);     // 12.58 MB
    u16* VT    = (u16*)(ws + 0x3E00000);     // 12.58 MB [D][KV]
    u16* Ob    = (u16*)(ws + 0x4A00000);     // 8.39 MB -> 0x5200000
    // FFN overlays (Qb..Ob dead then):
    u16* Gb16  = (u16*)(ws + 0x1E00000);     // 16.78 MB bf16 [S][F]
    u16* Ub16  = (u16*)(ws + 0x2E00000);     // 16.78 MB bf16 [S][F]
    u16* tb    = (u16*)(ws + 0x3E00000);     // 16.78 MB bf16 [S][F] -> 0x4E00000
    // split-K partial buffers:
    float* P0  = (float*)(ws + 0x52000000 - 0x4D000000);  // see below
    // (use fixed offsets to stay clear of overlays and weights)
    P0         = (float*)(ws + 0x5200000);   // 16.78 MB f32 [S][D]
    float* P1  = (float*)(ws + 0x6200000);   // 16.78 MB -> 0x7200000? (0x6200000+0x1000000)
    // lm partials [S][V] f32 (attn/FFN buffers dead at lm time):
    float* PL0 = (float*)(ws + 0x1E00000);   // 33.55 MB
    float* PL1 = (float*)(ws + 0x3E00000);   // 33.55 MB -> 0x5E00000
    // bf16 weights (converted once per call):
    u16* Wqb  = (u16*)(ws + 0x08000000);
    u16* Wkb  = (u16*)(ws + 0x0C000000);
    u16* Wvb  = (u16*)(ws + 0x10000000);
    u16* Wob  = (u16*)(ws + 0x14000000);
    u16* Wmkb = (u16*)(ws + 0x18000000);
    u16* Wmvb = (u16*)(ws + 0x1C000000);
    u16* Wgb  = (u16*)(ws + 0x20000000);
    u16* Wub  = (u16*)(ws + 0x28000000);
    u16* Wdb  = (u16*)(ws + 0x30000000);
    u16* lmb  = (u16*)(ws + 0x38000000);     // end 0x3C000000 (~1 GB)

    // ---- merged weight conversion (1 launch) ----
    const int nDD = L_ * D_ * D_ / 4, nFD = L_ * F_ * D_ / 4, nVD = V_ * D_ / 4;
    CvtBatch C{};
    const float* srcs[10] = {Wq, Wk, Wv, Wo, Wmk, Wmv, Wg, Wu, Wd, lm};
    u16* dsts[10] = {Wqb, Wkb, Wvb, Wob, Wmkb, Wmvb, Wgb, Wub, Wdb, lmb};
    int ns[10] = {nDD, nDD, nDD, nDD, nDD, nDD, nFD, nFD, nFD, nVD};
    int acc0 = 0;
    for (int s = 0; s < 10; ++s) {
        C.src[s] = srcs[s]; C.dst[s] = dsts[s];
        C.off[s] = acc0; acc0 += ns[s];
    }
    C.off[10] = acc0;
    k_cvtall<<<(acc0 + 255) / 256, 256, 0, stream>>>(C, acc0);

    k_embed<<<S_, 256, 0, stream>>>(ids, embed, h);
    k_ropetab<<<KV_, 64, 0, stream>>>(tab);
    k_rms<<<S_, 256, 0, stream>>>(h, ln1, xb);  // ln1[0]

    for (int l = 0; l < L_; ++l) {
        const size_t oDD = (size_t)l * D_ * D_;
        const size_t oFD = (size_t)l * F_ * D_;

        k_cvt<<<(M_ * D_ / 4 + 255) / 256, 256, 0, stream>>>(
            memory + (size_t)l * M_ * D_, memb, M_ * D_ / 4);

        // QKV + memory-KV: 8-phase 256^2, 5 z-slices
        GemmB8 g1{};
        g1.A[0] = xb;   g1.B[0] = Wqb + oDD;  g1.O[0] = Qb;                    g1.mrows[0] = S_;
        g1.A[1] = xb;   g1.B[1] = Wkb + oDD;  g1.O[1] = Kb + (size_t)M_ * D_;  g1.mrows[1] = S_;
        g1.A[2] = xb;   g1.B[2] = Wvb + oDD;  g1.O[2] = Vb + (size_t)M_ * D_;  g1.mrows[2] = S_;
        g1.A[3] = memb; g1.B[3] = Wmkb + oDD; g1.O[3] = Kb;                    g1.mrows[3] = M_;
        g1.A[4] = memb; g1.B[4] = Wmvb + oDD; g1.O[4] = Vb;                    g1.mrows[4] = M_;
        k_gemm8<0><<<dim3(D_ / 256, S_ / 256, 5), 512, 0, stream>>>(g1, D_, D_);

        k_rope2<<<S_ + KV_, 256, 0, stream>>>(Qb, Kb, tab);
        k_transpose<<<dim3(D_ / 64, KV_ / 64), 256, 0, stream>>>(Vb, VT);
        k_attn<<<dim3(S_ / 16, H_), 64, 0, stream>>>(Qb, Kb, VT, Ob);

        // Wo: 2ph split-K=2 into P0/P1 (no atomics), then fused add+rms(ln2)
        GemmB2 g2{};
        g2.A[0] = Ob; g2.B[0] = Wob + oDD; g2.O[0] = P0; g2.mrows[0] = S_; g2.koff[0] = 0;
        g2.A[1] = Ob; g2.B[1] = Wob + oDD; g2.O[1] = P1; g2.mrows[1] = S_; g2.koff[1] = 2048;
        k_gemm2<1><<<dim3(D_ / 128, S_ / 128, 2), 256, 0, stream>>>(g2, D_, 2048, D_);
        k_addrms<<<S_, 256, 0, stream>>>(h, P0, P1, ln2 + l * D_, xb);

        // FFN
        GemmB8 g3{};
        g3.A[0] = xb; g3.B[0] = Wgb + oFD; g3.O[0] = Gb16; g3.mrows[0] = S_;
        g3.A[1] = xb; g3.B[1] = Wub + oFD; g3.O[1] = Ub16; g3.mrows[1] = S_;
        k_gemm8<0><<<dim3(F_ / 256, S_ / 256, 2), 512, 0, stream>>>(g3, F_, D_);
        k_silu<<<(S_ * F_ / 8 + 255) / 256, 256, 0, stream>>>(Gb16, Ub16, tb, S_ * F_ / 8);

        // Wd: 2ph split-K=2 into P0/P1, then fused add+rms(next ln1 / normw)
        GemmB2 g5{};
        g5.A[0] = tb; g5.B[0] = Wdb + oFD; g5.O[0] = P0; g5.mrows[0] = S_; g5.koff[0] = 0;
        g5.A[1] = tb; g5.B[1] = Wdb + oFD; g5.O[1] = P1; g5.mrows[1] = S_; g5.koff[1] = 4096;
        k_gemm2<1><<<dim3(D_ / 128, S_ / 128, 2), 256, 0, stream>>>(g5, D_, 4096, F_);
        const float* nw = (l + 1 < L_) ? (ln1 + (l + 1) * D_) : normw;
        k_addrms<<<S_, 256, 0, stream>>>(h, P0, P1, nw, xb);
    }

    // logits: 2ph split-K=2 into PL0/PL1, then d_out = PL0+PL1
    GemmB2 g6{};
    g6.A[0] = xb; g6.B[0] = lmb; g6.O[0] = PL0; g6.mrows[0] = S_; g6.koff[0] = 0;
    g6.A[1] = xb; g6.B[1] = lmb; g6.O[1] = PL1; g6.mrows[1] = S_; g6.koff[1] = 2048;
    k_gemm2<1><<<dim3(V_ / 128, S_ / 128, 2), 256, 0, stream>>>(g6, V_, 2048, D_);
    k_add2<<<(S_ * V_ / 4 + 255) / 256, 256, 0, stream>>>(PL0, PL1, (float*)d_out, S_ * V_ / 4);
}